// Round 8
// baseline (132.649 us; speedup 1.0000x reference)
//
#include <hip/hip_runtime.h>

#define BB 2
#define LL 16
#define CC 16
#define HH 64
#define WW 64
#define HWSZ (HH * WW)
#define NCHUNK 64   // (j, i0) chunks: i in {i0, min(i0+1,15)}, covering all i>j

// chunk tables: for each j, i0 walks j+1, j+3, j+5, ... (chunks of <=2 i's)
__device__ __constant__ signed char CH_J[NCHUNK] = {
    0,0,0,0,0,0,0,0,
    1,1,1,1,1,1,1,
    2,2,2,2,2,2,2,
    3,3,3,3,3,3,
    4,4,4,4,4,4,
    5,5,5,5,5,
    6,6,6,6,6,
    7,7,7,7,
    8,8,8,8,
    9,9,9,
    10,10,10,
    11,11,
    12,12,
    13,
    14};
__device__ __constant__ signed char CH_I0[NCHUNK] = {
    1,3,5,7,9,11,13,15,
    2,4,6,8,10,12,14,
    3,5,7,9,11,13,15,
    4,6,8,10,12,14,
    5,7,9,11,13,15,
    6,8,10,12,14,
    7,9,11,13,15,
    8,10,12,14,
    9,11,13,15,
    10,12,14,
    11,13,15,
    12,14,
    13,15,
    14,
    15};

// ws layout: [0, 1MB) cum2 as (B, L, HW) float2;
//            [1MB, 9MB) quad-planar images qp[(bl*4 + qs)*HWSZ + pix] = float4 of
//            channels qs*4 .. qs*4+3 at pixel pix.
#define CUM2_FLOATS (BB * LL * HWSZ * 2)   // 262144

// ---- Fused prep kernel (unchanged from R7, correctness-verified) ----
__global__ __launch_bounds__(256) void gsp_prep(
    const float* __restrict__ flows,   // (B, L, 2, H, W)
    const float* __restrict__ images,  // (B, L, C, H, W)
    float2* __restrict__ cum2,         // (B, L, HW) float2
    float4* __restrict__ qp,           // (B*L, 4, HW) float4 quad-planes
    float* __restrict__ out)           // (B, L, C, H, W)
{
    if (blockIdx.x < 32) {
        const int gid = blockIdx.x * 256 + threadIdx.x;   // 0..8191
        const int b   = gid >> 12;
        const int pix = gid & (HWSZ - 1);
        const float* fb = flows + (size_t)b * LL * 2 * HWSZ + pix;
        float vx[LL], vy[LL];
        #pragma unroll
        for (int l = 0; l < LL; ++l) {
            vx[l] = fb[(size_t)l * 2 * HWSZ];
            vy[l] = fb[(size_t)l * 2 * HWSZ + HWSZ];
        }
        #pragma unroll
        for (int l = 1; l < LL; ++l) { vx[l] += vx[l - 1]; vy[l] += vy[l - 1]; }
        float2* cb = cum2 + (size_t)b * LL * HWSZ + pix;
        #pragma unroll
        for (int l = 0; l < LL; ++l) {
            float2 v; v.x = vx[l]; v.y = vy[l];
            cb[(size_t)l * HWSZ] = v;
        }
    } else {
        const int gid  = (blockIdx.x - 32) * 256 + threadIdx.x;  // 0..524287
        const int quad = gid & 3;
        const int pix  = (gid >> 2) & (HWSZ - 1);
        const int bl   = gid >> 14;

        const float* src = images + (size_t)(bl * CC + quad * 4) * HWSZ + pix;
        float4 v;
        v.x = src[0 * HWSZ];
        v.y = src[1 * HWSZ];
        v.z = src[2 * HWSZ];
        v.w = src[3 * HWSZ];
        qp[((size_t)bl * 4 + quad) * HWSZ + pix] = v;

        // identity term (j == i samples land exactly on integer pixel centers)
        float* op = out + (size_t)(bl * CC + quad * 4) * HWSZ + pix;
        op[0 * HWSZ] = v.x;
        op[1 * HWSZ] = v.y;
        op[2 * HWSZ] = v.z;
        op[3 * HWSZ] = v.w;
    }
}

// ---- Chunk kernel: block = (b, qs, chunk=(j, <=2 i's)). Stage plane (b,j,qs)
//      in LDS once (64 KB, 2 blocks/CU), then for each i in the chunk gather
//      bilinear corners via ds_read_b128 and commit with coalesced atomics. ----
__global__ __launch_bounds__(256, 2) void gsp_chunk(
    const float2* __restrict__ cum2,   // (B, L, HW) float2
    const float4* __restrict__ qp,     // (B*L, 4, HW) float4 quad-planes
    float* __restrict__ out)           // (B, L, C, H, W)
{
    __shared__ float4 tile[HWSZ];      // 64 KB

    const int chunk = blockIdx.x & 63;
    const int qs    = (blockIdx.x >> 6) & 3;
    const int b     = blockIdx.x >> 8;

    const int j  = CH_J[chunk];
    const int i0 = CH_I0[chunk];
    const int i1 = min(i0 + 1, LL - 1);

    const float2* cum_b = cum2 + (size_t)b * LL * HWSZ;

    // stage plane (b, j, qs): contiguous 64 KB, coalesced
    {
        const float4* src = qp + ((size_t)(b * LL + j) * 4 + qs) * HWSZ;
        #pragma unroll
        for (int it = 0; it < 16; ++it)
            tile[it * 256 + threadIdx.x] = src[it * 256 + threadIdx.x];
    }

    // preload cum_j for this thread's 16 pixels (i-independent)
    float2 cj[16];
    #pragma unroll
    for (int it = 0; it < 16; ++it)
        cj[it] = cum_b[(size_t)j * HWSZ + it * 256 + threadIdx.x];

    __syncthreads();

    for (int i = i0; i <= i1; i += (i1 > i0 ? 1 : 2)) {
        float* op = out + ((size_t)(b * LL + i) * CC + qs * 4) * HWSZ;

        #pragma unroll
        for (int it = 0; it < 16; ++it) {
            const int px = it * 256 + threadIdx.x;
            const int h = px >> 6;
            const int w = px & (WW - 1);

            const float2 ci = cum_b[(size_t)i * HWSZ + px];

            float gx = (w + 0.5f) * (2.0f / WW) - 1.0f + (ci.x - cj[it].x);
            float gy = (h + 0.5f) * (2.0f / HH) - 1.0f + (ci.y - cj[it].y);

            // gx = remainder(gx + 1, 2) - 1
            float tt = gx + 1.0f;
            tt = tt - floorf(tt * 0.5f) * 2.0f;
            gx = tt - 1.0f;

            const float ix = ((gx + 1.0f) * WW - 1.0f) * 0.5f;
            const float iy = ((gy + 1.0f) * HH - 1.0f) * 0.5f;
            const float x0f = floorf(ix);
            const float y0f = floorf(iy);
            const float fx = ix - x0f;
            const float fy = iy - y0f;
            const int x0 = (int)x0f;
            const int y0 = (int)y0f;
            const int x1 = x0 + 1;
            const int y1 = y0 + 1;

            const bool vx0 = (x0 >= 0) && (x0 < WW);
            const bool vx1 = (x1 >= 0) && (x1 < WW);
            const bool vy0 = (y0 >= 0) && (y0 < HH);
            const bool vy1 = (y1 >= 0) && (y1 < HH);

            const int cx0 = min(max(x0, 0), WW - 1);
            const int cx1 = min(max(x1, 0), WW - 1);
            const int cy0 = min(max(y0, 0), HH - 1);
            const int cy1 = min(max(y1, 0), HH - 1);

            const float w00 = ((vx0 && vy0) ? 1.0f : 0.0f) * (1.0f - fx) * (1.0f - fy);
            const float w01 = ((vx1 && vy0) ? 1.0f : 0.0f) * fx * (1.0f - fy);
            const float w10 = ((vx0 && vy1) ? 1.0f : 0.0f) * (1.0f - fx) * fy;
            const float w11 = ((vx1 && vy1) ? 1.0f : 0.0f) * fx * fy;

            const float4 v00 = tile[cy0 * WW + cx0];
            const float4 v01 = tile[cy0 * WW + cx1];
            const float4 v10 = tile[cy1 * WW + cx0];
            const float4 v11 = tile[cy1 * WW + cx1];

            const float ax = w00 * v00.x + w01 * v01.x + w10 * v10.x + w11 * v11.x;
            const float ay = w00 * v00.y + w01 * v01.y + w10 * v10.y + w11 * v11.y;
            const float az = w00 * v00.z + w01 * v01.z + w10 * v10.z + w11 * v11.z;
            const float aw = w00 * v00.w + w01 * v01.w + w10 * v10.w + w11 * v11.w;

            atomicAdd(op + 0 * HWSZ + px, ax);
            atomicAdd(op + 1 * HWSZ + px, ay);
            atomicAdd(op + 2 * HWSZ + px, az);
            atomicAdd(op + 3 * HWSZ + px, aw);
        }
    }
}

extern "C" void kernel_launch(void* const* d_in, const int* in_sizes, int n_in,
                              void* d_out, int out_size, void* d_ws, size_t ws_size,
                              hipStream_t stream) {
    const float* flows  = (const float*)d_in[0];
    const float* images = (const float*)d_in[1];
    float* out = (float*)d_out;
    float2* cum2 = (float2*)d_ws;                       // 1 MB
    float*  qp   = (float*)d_ws + CUM2_FLOATS;          // 8 MB quad-planar

    gsp_prep<<<32 + 2048, 256, 0, stream>>>(flows, images, cum2, (float4*)qp, out);

    const int grid = BB * 4 * NCHUNK;                   // 512 blocks x 256 threads
    gsp_chunk<<<grid, 256, 0, stream>>>(cum2, (const float4*)qp, out);
}

// Round 10
// 89.888 us; speedup vs baseline: 1.4757x; 1.4757x over previous
//
#include <hip/hip_runtime.h>

#define BB 2
#define LL 16
#define CC 16
#define HH 64
#define WW 64
#define HWSZ (HH * WW)
#define NSEG 36   // per i: ceil(i/4) width-4 (padded) j-segments, i = 1..15

__device__ __constant__ int SEG_I[NSEG] = {
    1, 2, 3, 4,
    5, 5, 6, 6, 7, 7, 8, 8,
    9, 9, 9, 10, 10, 10, 11, 11, 11, 12, 12, 12,
    13, 13, 13, 13, 14, 14, 14, 14, 15, 15, 15, 15};
__device__ __constant__ int SEG_J0[NSEG] = {
    0, 0, 0, 0,
    0, 4, 0, 4, 0, 4, 0, 4,
    0, 4, 8, 0, 4, 8, 0, 4, 8, 0, 4, 8,
    0, 4, 8, 12, 0, 4, 8, 12, 0, 4, 8, 12};

// per-i segment lists (indices into the tables above)
__device__ __constant__ signed char NSEG_OF_I[LL] = {0,1,1,1,1,2,2,2,2,3,3,3,3,4,4,4};
__device__ __constant__ signed char SEG_OF_I[LL][4] = {
    {0,0,0,0},   // i=0 (unused)
    {0,0,0,0}, {1,0,0,0}, {2,0,0,0}, {3,0,0,0},
    {4,5,0,0}, {6,7,0,0}, {8,9,0,0}, {10,11,0,0},
    {12,13,14,0}, {15,16,17,0}, {18,19,20,0}, {21,22,23,0},
    {24,25,26,27}, {28,29,30,31}, {32,33,34,35}};

// ws layout (floats):
//   [0, 262144)        cum2  (B, L, HW) float2                  = 1 MB
//   [262144, 2359296)  nhwc  (B*L, HW, 4quad) float4 interleaved = 8 MB
//   [2359296, 7077888) partial (B, NSEG, HW, 4quad) float4       = 18 MB
#define CUM2_FLOATS (BB * LL * HWSZ * 2)
#define QP_FLOATS   (BB * LL * CC * HWSZ)

// ---- prep: cumsum -> cum2; NCHW -> interleaved NHWC (pixel's 4 quads = one 64B line) ----
__global__ __launch_bounds__(256) void gsp_prep(
    const float* __restrict__ flows,   // (B, L, 2, H, W)
    const float* __restrict__ images,  // (B, L, C, H, W)
    float2* __restrict__ cum2,         // (B, L, HW) float2
    float4* __restrict__ nhwc)         // (B*L, HW, 4) float4 quads, interleaved
{
    if (blockIdx.x < 32) {
        const int gid = blockIdx.x * 256 + threadIdx.x;   // 0..8191
        const int b   = gid >> 12;
        const int pix = gid & (HWSZ - 1);
        const float* fb = flows + (size_t)b * LL * 2 * HWSZ + pix;
        float vx[LL], vy[LL];
        #pragma unroll
        for (int l = 0; l < LL; ++l) {
            vx[l] = fb[(size_t)l * 2 * HWSZ];
            vy[l] = fb[(size_t)l * 2 * HWSZ + HWSZ];
        }
        #pragma unroll
        for (int l = 1; l < LL; ++l) { vx[l] += vx[l - 1]; vy[l] += vy[l - 1]; }
        float2* cb = cum2 + (size_t)b * LL * HWSZ + pix;
        #pragma unroll
        for (int l = 0; l < LL; ++l) {
            float2 v; v.x = vx[l]; v.y = vy[l];
            cb[(size_t)l * HWSZ] = v;
        }
    } else {
        const int gid  = (blockIdx.x - 32) * 256 + threadIdx.x;  // 0..524287
        const int quad = gid & 3;
        const int pix  = (gid >> 2) & (HWSZ - 1);
        const int bl   = gid >> 14;

        const float* src = images + (size_t)(bl * CC + quad * 4) * HWSZ + pix;
        float4 v;
        v.x = src[0 * HWSZ];
        v.y = src[1 * HWSZ];
        v.z = src[2 * HWSZ];
        v.w = src[3 * HWSZ];
        nhwc[((size_t)bl * HWSZ + pix) * 4 + quad] = v;
    }
}

// ---- pairs: j<i contributions per width-4 segment; NO atomics — each block
//      streams its segment-partial (one float4 per (pix,quad)) to ws. ----
__global__ __launch_bounds__(256) void gsp_pairs(
    const float2* __restrict__ cum2,   // (B, L, HW) float2
    const float4* __restrict__ nhwc,   // (B*L, HW, 4) float4, interleaved
    float4* __restrict__ partial)      // (B, NSEG, HW, 4) float4
{
    const int tile = blockIdx.x & 63;            // 64 tiles of 64 pixels
    const int seg  = (blockIdx.x >> 6) % NSEG;
    const int b    = blockIdx.x / (64 * NSEG);

    const int i    = SEG_I[seg];
    const int j0   = SEG_J0[seg];
    const int jmax = i - 1;

    const int psub = threadIdx.x >> 2;           // 0..63
    const int quad = threadIdx.x & 3;            // channel quad
    const int pix  = tile * 64 + psub;           // 0..4095
    const int h = pix >> 6;
    const int w = pix & (WW - 1);

    const float2* cum_b  = cum2 + (size_t)b * LL * HWSZ + pix;
    const float4* nhwc_b = nhwc + (size_t)b * LL * HWSZ * 4;

    const float gxb = (w + 0.5f) * (2.0f / WW) - 1.0f;
    const float gyb = (h + 0.5f) * (2.0f / HH) - 1.0f;

    // phase 1: cum loads (5 independent)
    const float2 ci = cum_b[(size_t)i * HWSZ];
    int    jj[4];
    float2 cj[4];
    #pragma unroll
    for (int k = 0; k < 4; ++k) {
        jj[k] = min(j0 + k, jmax);
        cj[k] = cum_b[(size_t)jj[k] * HWSZ];
    }

    // phase 2: addresses + masks + fractions
    int   off[16];
    float fxk[4], fyk[4];
    float m00[4], m01[4], m10[4], m11[4];
    #pragma unroll
    for (int k = 0; k < 4; ++k) {
        float gx = gxb + (ci.x - cj[k].x);
        float gy = gyb + (ci.y - cj[k].y);

        // gx = remainder(gx + 1, 2) - 1
        float tt = gx + 1.0f;
        tt = tt - floorf(tt * 0.5f) * 2.0f;
        gx = tt - 1.0f;

        const float ix = ((gx + 1.0f) * WW - 1.0f) * 0.5f;
        const float iy = ((gy + 1.0f) * HH - 1.0f) * 0.5f;
        const float x0f = floorf(ix);
        const float y0f = floorf(iy);
        fxk[k] = ix - x0f;
        fyk[k] = iy - y0f;
        const int x0 = (int)x0f;
        const int y0 = (int)y0f;
        const int x1 = x0 + 1;
        const int y1 = y0 + 1;

        const bool vx0 = (x0 >= 0) && (x0 < WW);
        const bool vx1 = (x1 >= 0) && (x1 < WW);
        const bool vy0 = (y0 >= 0) && (y0 < HH);
        const bool vy1 = (y1 >= 0) && (y1 < HH);
        const float wpad = (j0 + k <= jmax) ? 1.0f : 0.0f;
        m00[k] = (vx0 && vy0) ? wpad : 0.0f;
        m01[k] = (vx1 && vy0) ? wpad : 0.0f;
        m10[k] = (vx0 && vy1) ? wpad : 0.0f;
        m11[k] = (vx1 && vy1) ? wpad : 0.0f;

        const int cx0 = min(max(x0, 0), WW - 1);
        const int cx1 = min(max(x1, 0), WW - 1);
        const int cy0 = min(max(y0, 0), HH - 1);
        const int cy1 = min(max(y1, 0), HH - 1);

        const int jbase = jj[k] * (HWSZ * 4) + quad;   // float4 units, interleaved
        off[k * 4 + 0] = jbase + (cy0 * WW + cx0) * 4;
        off[k * 4 + 1] = jbase + (cy0 * WW + cx1) * 4;
        off[k * 4 + 2] = jbase + (cy1 * WW + cx0) * 4;
        off[k * 4 + 3] = jbase + (cy1 * WW + cx1) * 4;
    }

    // phase 3: 16 independent gathers in flight
    float4 v[16];
    #pragma unroll
    for (int m = 0; m < 16; ++m) v[m] = nhwc_b[off[m]];

    // phase 4: weights under the loads
    float wgt[16];
    #pragma unroll
    for (int k = 0; k < 4; ++k) {
        const float fx = fxk[k], fy = fyk[k];
        wgt[k * 4 + 0] = m00[k] * (1.0f - fx) * (1.0f - fy);
        wgt[k * 4 + 1] = m01[k] * fx * (1.0f - fy);
        wgt[k * 4 + 2] = m10[k] * (1.0f - fx) * fy;
        wgt[k * 4 + 3] = m11[k] * fx * fy;
    }

    // phase 5: reduce + single coalesced partial store (no atomics)
    float4 s; s.x = 0.0f; s.y = 0.0f; s.z = 0.0f; s.w = 0.0f;
    #pragma unroll
    for (int m = 0; m < 16; ++m) {
        s.x += wgt[m] * v[m].x;
        s.y += wgt[m] * v[m].y;
        s.z += wgt[m] * v[m].z;
        s.w += wgt[m] * v[m].w;
    }
    partial[((size_t)(b * NSEG + seg) * HWSZ + pix) * 4 + quad] = s;
}

// ---- reduce: out = identity (from nhwc) + sum of this i's segment partials ----
__global__ __launch_bounds__(256) void gsp_reduce(
    const float4* __restrict__ nhwc,     // (B*L, HW, 4) float4, interleaved
    const float4* __restrict__ partial,  // (B, NSEG, HW, 4) float4
    float* __restrict__ out)             // (B, L, C, H, W)
{
    const int gid  = blockIdx.x * 256 + threadIdx.x;  // 0..524287
    const int quad = gid & 3;
    const int pix  = (gid >> 2) & (HWSZ - 1);
    const int bl   = gid >> 14;
    const int b    = bl >> 4;
    const int i    = bl & 15;

    // j == i identity term (samples land exactly on integer pixel centers)
    float4 s = nhwc[((size_t)bl * HWSZ + pix) * 4 + quad];

    const int n = NSEG_OF_I[i];
    for (int k = 0; k < n; ++k) {                     // wave-uniform trip count
        const int seg = SEG_OF_I[i][k];
        const float4 p = partial[((size_t)(b * NSEG + seg) * HWSZ + pix) * 4 + quad];
        s.x += p.x; s.y += p.y; s.z += p.z; s.w += p.w;
    }

    float* op = out + ((size_t)bl * CC + quad * 4) * HWSZ + pix;
    op[0 * HWSZ] = s.x;
    op[1 * HWSZ] = s.y;
    op[2 * HWSZ] = s.z;
    op[3 * HWSZ] = s.w;
}

extern "C" void kernel_launch(void* const* d_in, const int* in_sizes, int n_in,
                              void* d_out, int out_size, void* d_ws, size_t ws_size,
                              hipStream_t stream) {
    const float* flows  = (const float*)d_in[0];
    const float* images = (const float*)d_in[1];
    float* out = (float*)d_out;
    float2* cum2    = (float2*)d_ws;
    float*  nhwc    = (float*)d_ws + CUM2_FLOATS;
    float4* partial = (float4*)((float*)d_ws + CUM2_FLOATS + QP_FLOATS);

    gsp_prep<<<32 + 2048, 256, 0, stream>>>(flows, images, cum2, (float4*)nhwc);

    const int grid = BB * NSEG * 64;                    // 4608 blocks
    gsp_pairs<<<grid, 256, 0, stream>>>(cum2, (const float4*)nhwc, partial);

    gsp_reduce<<<2048, 256, 0, stream>>>((const float4*)nhwc, partial, out);
}